// Round 12
// baseline (165.756 us; speedup 1.0000x reference)
//
#include <hip/hip_runtime.h>
#include <hip/hip_bf16.h>

#define NUM_HEADS 4
#define HD 256
#define QD 256
#define VD 256
#define B_SZ 32
#define N_NODES 8192
#define NEG_SLOPE 0.2f

typedef short bf16x8 __attribute__((ext_vector_type(8)));
typedef float f32x4 __attribute__((ext_vector_type(4)));

static __device__ __forceinline__ unsigned short f2bf(float f) {
    __hip_bfloat16 h = __float2bfloat16(f);
    return *reinterpret_cast<unsigned short*>(&h);
}

// ---------------------------------------------------------------------------
// Kernel 1: prep
//  blocks 0..31 : hqb[b][col] = query[b]@Wq[:,col] + 2*bq[col]
//  blocks 32..63: pack Wq -> bf16, SWIZZLED fragment order (conflict-free
//  lane-linear ds_read_b128 per (ks,h,ct)).
// ---------------------------------------------------------------------------
__global__ __launch_bounds__(256)
void prep_kernel(const float* __restrict__ query,
                 const float* __restrict__ Wq,
                 const float* __restrict__ bq,
                 unsigned short* __restrict__ WqP,
                 float* __restrict__ hqb) {
    int blk = blockIdx.x;
    int tid = threadIdx.x;
    if (blk < 32) {
        int b = blk, col = tid;
        float acc = 2.0f * bq[col];
#pragma unroll 16
        for (int k = 0; k < QD; ++k)
            acc += query[b * QD + k] * Wq[k * HD + col];
        hqb[b * HD + col] = acc;
    } else {
        int idx = blk - 32;
        int kstep = idx >> 2, g = idx & 3;
        int col = tid;                 // global column 0..255
        int h = col >> 6, ct = (col >> 4) & 3, col16 = col & 15;
        unsigned short v[8];
#pragma unroll
        for (int j = 0; j < 8; ++j)
            v[j] = f2bf(Wq[(kstep * 32 + g * 8 + j) * HD + col]);
        *reinterpret_cast<uint4*>(
            WqP + kstep * 8192 + h * 2048 + ct * 512 + (g * 16 + col16) * 8) =
            *reinterpret_cast<uint4*>(v);
    }
}

// ---------------------------------------------------------------------------
// Kernel 2 (FUSED, persistent waves + FORCED load burst):
// Identical to R11 except ONE change: sched_barrier(0) after the 32-load
// burst, preventing the compiler from sinking loads to their uses (which
// R11's VGPR_Count=128 proved it was doing). Burst stays 32-deep in flight;
// first cvt waits only on kf[0] (vmcnt retires in order; kf issued first).
// ---------------------------------------------------------------------------
__global__ __launch_bounds__(512, 2)
void fused_kernel(const float* __restrict__ key,
                  const float* __restrict__ value,
                  const unsigned short* __restrict__ WqP,
                  const float* __restrict__ hqb,
                  const float* __restrict__ avec,
                  float* __restrict__ s,
                  float* __restrict__ p_part,
                  float* __restrict__ pml) {
    __shared__ __align__(16) unsigned short wq[65536];   // 128 KB, read-only after stage

    int bid = blockIdx.x;
    int b = bid >> 3, blk8 = bid & 7;
    int tid = threadIdx.x;
    int w = tid >> 6, lane = tid & 63;
    int col16 = lane & 15, g = (lane >> 4) & 3;

    // ---- stage full WqP -> LDS (lane-linear copy), once
    {
        const uint4* src = reinterpret_cast<const uint4*>(WqP);
        uint4* dst = reinterpret_cast<uint4*>(wq);
#pragma unroll
        for (int j = 0; j < 16; ++j)
            dst[tid + j * 512] = src[tid + j * 512];
    }
    float av4[4];
#pragma unroll
    for (int ct = 0; ct < 4; ++ct) av4[ct] = avec[ct * 16 + col16];
    __syncthreads();   // wq ready; LAST barrier in the kernel

    // ---- running online-softmax state (per wave, per head)
    float mr[4] = {-1e30f, -1e30f, -1e30f, -1e30f};
    float lr[4] = {0.f, 0.f, 0.f, 0.f};
    f32x4 pa[4];
#pragma unroll
    for (int h = 0; h < 4; ++h) pa[h] = (f32x4){0.f, 0.f, 0.f, 0.f};

    for (int c = 0; c < 8; ++c) {
        int n0 = blk8 * 1024 + c * 128 + w * 16;

        // ---- issue key burst FIRST (consumed first), then value burst.
        //      32 loads, 128 VGPRs of destination, all in flight together.
        f32x4 kf[16];
        {
            const float* kb = key + ((size_t)(b * N_NODES + n0 + col16)) * QD + g * 8;
#pragma unroll
            for (int ks = 0; ks < 8; ++ks) {
                kf[ks * 2]     = *reinterpret_cast<const f32x4*>(kb + ks * 32);
                kf[ks * 2 + 1] = *reinterpret_cast<const f32x4*>(kb + ks * 32 + 4);
            }
        }
        f32x4 vv[16];
        {
            const float* vb = value + ((size_t)(b * N_NODES + n0)) * VD + lane * 4;
#pragma unroll
            for (int n = 0; n < 16; ++n)
                vv[n] = *reinterpret_cast<const f32x4*>(vb + (size_t)n * VD);
        }
        // THE experiment: forbid sinking any of the 32 loads below this point.
        __builtin_amdgcn_sched_barrier(0);

        // ---- cvt key -> A-fragments (kf dies here; waits only on kf arrivals)
        bf16x8 a[8];
#pragma unroll
        for (int ks = 0; ks < 8; ++ks) {
            unsigned int u0, u1, u2, u3;
            asm("v_cvt_pk_bf16_f32 %0, %1, %2" : "=v"(u0) : "v"(kf[ks*2][0]), "v"(kf[ks*2][1]));
            asm("v_cvt_pk_bf16_f32 %0, %1, %2" : "=v"(u1) : "v"(kf[ks*2][2]), "v"(kf[ks*2][3]));
            asm("v_cvt_pk_bf16_f32 %0, %1, %2" : "=v"(u2) : "v"(kf[ks*2+1][0]), "v"(kf[ks*2+1][1]));
            asm("v_cvt_pk_bf16_f32 %0, %1, %2" : "=v"(u3) : "v"(kf[ks*2+1][2]), "v"(kf[ks*2+1][3]));
            uint4 t = {u0, u1, u2, u3};
            a[ks] = *reinterpret_cast<bf16x8*>(&t);
        }

        // ---- per-head MFMA (conflict-free B from LDS) + epilogue + online SM
        float epv[4][4];
#pragma unroll
        for (int h = 0; h < 4; ++h) {
            f32x4 acc[4];
#pragma unroll
            for (int ct = 0; ct < 4; ++ct) acc[ct] = (f32x4){0.f, 0.f, 0.f, 0.f};
#pragma unroll
            for (int ks = 0; ks < 8; ++ks) {
                const unsigned short* wp = wq + ks * 8192 + h * 2048 + (g * 16 + col16) * 8;
#pragma unroll
                for (int ct = 0; ct < 4; ++ct) {
                    bf16x8 bf = *reinterpret_cast<const bf16x8*>(wp + ct * 512);
                    acc[ct] = __builtin_amdgcn_mfma_f32_16x16x32_bf16(a[ks], bf, acc[ct], 0, 0, 0);
                }
            }
            float part[4] = {0.f, 0.f, 0.f, 0.f};
#pragma unroll
            for (int ct = 0; ct < 4; ++ct) {
                float hq_ = hqb[b * HD + h * 64 + ct * 16 + col16];
#pragma unroll
                for (int r = 0; r < 4; ++r) {
                    float pre = acc[ct][r] + hq_;
                    float t = fmaxf(pre, NEG_SLOPE * pre);
                    part[r] += av4[ct] * t;
                }
            }
#pragma unroll
            for (int off = 1; off < 16; off <<= 1)
#pragma unroll
                for (int r = 0; r < 4; ++r)
                    part[r] += __shfl_xor(part[r], off, 64);
            if (col16 == 0) {
                float4 sv4 = {part[0], part[1], part[2], part[3]};
                *reinterpret_cast<float4*>(
                    s + ((size_t)(b * NUM_HEADS + h)) * N_NODES + n0 + g * 4) = sv4;
            }
            float mc = fmaxf(fmaxf(part[0], part[1]), fmaxf(part[2], part[3]));
            mc = fmaxf(mc, __shfl_xor(mc, 16, 64));
            mc = fmaxf(mc, __shfl_xor(mc, 32, 64));
            float mnew = fmaxf(mr[h], mc);
            float lc = 0.f;
#pragma unroll
            for (int r = 0; r < 4; ++r) { epv[h][r] = __expf(part[r] - mnew); lc += epv[h][r]; }
            lc += __shfl_xor(lc, 16, 64);
            lc += __shfl_xor(lc, 32, 64);
            float sc_ = __expf(mr[h] - mnew);
            pa[h] *= sc_;
            lr[h] = lr[h] * sc_ + lc;
            mr[h] = mnew;
        }

        // ---- PV: broadcast exp-scores, accumulate into running pa (vv dies)
#pragma unroll
        for (int n = 0; n < 16; ++n) {
#pragma unroll
            for (int h = 0; h < 4; ++h) {
                float e = __shfl(epv[h][n & 3], (n >> 2) * 16, 64);
                pa[h] += e * vv[n];
            }
        }
    }

    // ---- per-wave output (chunk id = blk8*8 + w), no barrier needed
    int chunkid = b * 64 + blk8 * 8 + w;
    float* pp = p_part + (size_t)chunkid * 1024;
#pragma unroll
    for (int h = 0; h < 4; ++h)
        *reinterpret_cast<f32x4*>(pp + h * 256 + lane * 4) = pa[h];
    if (lane == 0) {
#pragma unroll
        for (int h = 0; h < 4; ++h) {
            pml[(size_t)chunkid * 8 + h] = mr[h];
            pml[(size_t)chunkid * 8 + 4 + h] = lr[h];
        }
    }
}

// ---------------------------------------------------------------------------
// Kernel 3: final. Per (b,h): global M,L over 64 wave-chunks; rescale-reduce
// p_part; @Wv + bias + relu; emit (M, invL) for epass.
// ---------------------------------------------------------------------------
__global__ __launch_bounds__(256)
void final_kernel(const float* __restrict__ p_part,
                  const float* __restrict__ pml,
                  const float* __restrict__ Wv,
                  const float* __restrict__ bv,
                  float* __restrict__ hout,
                  float* __restrict__ sc) {
    int bh = blockIdx.x;
    int b = bh >> 2, h = bh & 3;
    int tid = threadIdx.x;
    int wv = tid >> 6, lane = tid & 63;

    float mc = -1e30f, lc = 0.f;
    if (tid < 64) {
        mc = pml[((size_t)(b * 64 + tid)) * 8 + h];
        lc = pml[((size_t)(b * 64 + tid)) * 8 + 4 + h];
    }

    __shared__ float r4a[4], r4b[4];
    __shared__ float wfs[64];
    float M = mc;
#pragma unroll
    for (int off = 1; off < 64; off <<= 1) M = fmaxf(M, __shfl_xor(M, off, 64));
    if (lane == 0) r4a[wv] = M;
    __syncthreads();
    M = fmaxf(fmaxf(r4a[0], r4a[1]), fmaxf(r4a[2], r4a[3]));

    float wf = (tid < 64) ? __expf(mc - M) : 0.f;
    if (tid < 64) wfs[tid] = wf;
    float Lp = wf * lc;
#pragma unroll
    for (int off = 1; off < 64; off <<= 1) Lp += __shfl_xor(Lp, off, 64);
    if (lane == 0) r4b[wv] = Lp;
    __syncthreads();
    float L = r4b[0] + r4b[1] + r4b[2] + r4b[3];
    float invL = 1.0f / L;
    if (tid == 0) {
        sc[bh * 2] = M;
        sc[bh * 2 + 1] = invL;
    }

    float acc = 0.f;
    const float* pp = p_part + ((size_t)(b * 64)) * 1024 + h * 256 + tid;
#pragma unroll 8
    for (int c = 0; c < 64; ++c)
        acc += wfs[c] * pp[(size_t)c * 1024];
    __shared__ float ps[256];
    ps[tid] = acc * invL;
    __syncthreads();

    int d = tid & 63, kr = tid >> 6;
    float a2 = 0.f;
#pragma unroll 8
    for (int k = kr * 64; k < kr * 64 + 64; ++k)
        a2 += ps[k] * Wv[k * HD + h * 64 + d];
    __shared__ float rs[4][64];
    rs[kr][d] = a2;
    __syncthreads();
    if (tid < 64) {
        float o = bv[h * 64 + tid] + rs[0][tid] + rs[1][tid] + rs[2][tid] + rs[3][tid];
        hout[b * HD + h * 64 + tid] = fmaxf(o, 0.f);
    }
}

// ---------------------------------------------------------------------------
// Kernel 4: e-pass. e_out[b,n,h] = exp(s[b,h,n]-M)*invL.
// ---------------------------------------------------------------------------
__global__ __launch_bounds__(256)
void epass_kernel(const float* __restrict__ s,
                  const float* __restrict__ sc,
                  float* __restrict__ e_out) {
    int bid = blockIdx.x;
    int b = bid >> 5, t = bid & 31;
    int n = t * 256 + threadIdx.x;
    float4 ev;
#pragma unroll
    for (int h = 0; h < 4; ++h) {
        float M = sc[(b * 4 + h) * 2];
        float invL = sc[(b * 4 + h) * 2 + 1];
        float sv = s[((size_t)(b * 4 + h)) * N_NODES + n];
        (&ev.x)[h] = __expf(sv - M) * invL;
    }
    *reinterpret_cast<float4*>(e_out + ((size_t)(b * N_NODES + n)) * 4) = ev;
}

extern "C" void kernel_launch(void* const* d_in, const int* in_sizes, int n_in,
                              void* d_out, int out_size, void* d_ws, size_t ws_size,
                              hipStream_t stream) {
    const float* query = (const float*)d_in[0];
    const float* key   = (const float*)d_in[1];
    const float* value = (const float*)d_in[2];
    const float* Wq    = (const float*)d_in[3];
    const float* bq    = (const float*)d_in[4];
    const float* Wv    = (const float*)d_in[5];
    const float* bv    = (const float*)d_in[6];
    const float* avec  = (const float*)d_in[7];
    float* out = (float*)d_out;

    char* ws = (char*)d_ws;
    unsigned short* WqP = (unsigned short*)ws;               // 128 KB
    float* hqb    = (float*)(ws + 131072);                   // 32 KB
    float* s      = (float*)(ws + 163840);                   // 4 MB
    float* pml    = (float*)(ws + 4358144);                  // 64 KB
    float* sc     = (float*)(ws + 4423680);                  // 4 KB
    float* p_part = (float*)(ws + 4427776);                  // 8 MB

    prep_kernel<<<64, 256, 0, stream>>>(query, Wq, bq, WqP, hqb);
    fused_kernel<<<256, 512, 0, stream>>>(key, value, WqP, hqb, avec, s, p_part, pml);
    final_kernel<<<B_SZ * NUM_HEADS, 256, 0, stream>>>(p_part, pml, Wv, bv, out, sc);
    epass_kernel<<<B_SZ * 32, 256, 0, stream>>>(s, sc, out + B_SZ * HD);
}

// Round 13
// 131.142 us; speedup vs baseline: 1.2639x; 1.2639x over previous
//
#include <hip/hip_runtime.h>
#include <hip/hip_bf16.h>

#define NUM_HEADS 4
#define HD 256
#define QD 256
#define VD 256
#define B_SZ 32
#define N_NODES 8192
#define NEG_SLOPE 0.2f
#define CH 32            // rows per chunk
#define NCH 32           // chunks per strip (1024 rows)
#define KSTRIDE 1040     // key LDS row stride bytes (1024 + 16 pad: kills bank aliasing)

typedef short bf16x8 __attribute__((ext_vector_type(8)));
typedef float f32x4 __attribute__((ext_vector_type(4)));

static __device__ __forceinline__ unsigned short f2bf(float f) {
    __hip_bfloat16 h = __float2bfloat16(f);
    return *reinterpret_cast<unsigned short*>(&h);
}

// async global->LDS, 16B/lane: LDS dest = base + lane*16; global src per-lane.
static __device__ __forceinline__ void gload_lds16(const float* g, void* l) {
    __builtin_amdgcn_global_load_lds(
        (const __attribute__((address_space(1))) void*)g,
        (__attribute__((address_space(3))) void*)l, 16, 0, 0);
}

// ---------------------------------------------------------------------------
// Kernel 1: prep  (unchanged: hqb + swizzled WqP pack)
// ---------------------------------------------------------------------------
__global__ __launch_bounds__(256)
void prep_kernel(const float* __restrict__ query,
                 const float* __restrict__ Wq,
                 const float* __restrict__ bq,
                 unsigned short* __restrict__ WqP,
                 float* __restrict__ hqb) {
    int blk = blockIdx.x;
    int tid = threadIdx.x;
    if (blk < 32) {
        int b = blk, col = tid;
        float acc = 2.0f * bq[col];
#pragma unroll 16
        for (int k = 0; k < QD; ++k)
            acc += query[b * QD + k] * Wq[k * HD + col];
        hqb[b * HD + col] = acc;
    } else {
        int idx = blk - 32;
        int kstep = idx >> 2, g = idx & 3;
        int col = tid;
        int h = col >> 6, ct = (col >> 4) & 3, col16 = col & 15;
        unsigned short v[8];
#pragma unroll
        for (int j = 0; j < 8; ++j)
            v[j] = f2bf(Wq[(kstep * 32 + g * 8 + j) * HD + col]);
        *reinterpret_cast<uint4*>(
            WqP + kstep * 8192 + h * 2048 + ct * 512 + (g * 16 + col16) * 8) =
            *reinterpret_cast<uint4*>(v);
    }
}

// ---------------------------------------------------------------------------
// Kernel 2 (FUSED, gload_lds pipeline + Wq-in-registers):
// grid 256 = (b, 1024-row strip), 512 thr, 1 block/CU (129 KB LDS).
// Wave w: head h=w&3, row-half half=w>>2 (rows half*16..+16 of each chunk).
// Per wave: 32 B-frags (128 VGPR) persistent. Per chunk (32 rows):
//   barrier -> issue 8 gload_lds for chunk t+1 -> vmcnt(8) -> barrier ->
//   {key LDS->cvt->a[8]; 32 MFMA; epilogue; online SM; PV from value LDS}.
// Loads always span one full compute phase; RA cannot serialize them.
// ---------------------------------------------------------------------------
__global__ __launch_bounds__(512, 2)
void fused_kernel(const float* __restrict__ key,
                  const float* __restrict__ value,
                  const unsigned short* __restrict__ WqP,
                  const float* __restrict__ hqb,
                  const float* __restrict__ avec,
                  float* __restrict__ s,
                  float* __restrict__ p_part,
                  float* __restrict__ pml) {
    __shared__ __align__(16) char smem[2 * (CH * KSTRIDE) + 2 * (CH * 1024)];  // 132096 B

    char* kb0 = smem;
    char* kb1 = smem + CH * KSTRIDE;
    char* vb0 = smem + 2 * CH * KSTRIDE;
    char* vb1 = vb0 + CH * 1024;

    int bid = blockIdx.x;
    int b = bid >> 3, strip = bid & 7;
    int tid = threadIdx.x;
    int w = tid >> 6, lane = tid & 63;
    int col16 = lane & 15, g = (lane >> 4) & 3;
    int h = w & 3, half = w >> 2;
    int rowbase0 = strip * 1024;

    // ---- persistent B-fragments for my head: 32 x bf16x8 = 128 VGPRs
    bf16x8 bfr[8][4];
    {
        const unsigned short* wp0 = WqP + h * 2048 + (g * 16 + col16) * 8;
#pragma unroll
        for (int ks = 0; ks < 8; ++ks)
#pragma unroll
            for (int ct = 0; ct < 4; ++ct)
                bfr[ks][ct] = *reinterpret_cast<const bf16x8*>(wp0 + ks * 8192 + ct * 512);
    }
    float av4[4], hq4[4];
#pragma unroll
    for (int ct = 0; ct < 4; ++ct) {
        av4[ct] = avec[ct * 16 + col16];
        hq4[ct] = hqb[b * HD + h * 64 + ct * 16 + col16];
    }

    // ---- running online-softmax state (single head)
    float mr = -1e30f, lr = 0.f;
    f32x4 pa = (f32x4){0.f, 0.f, 0.f, 0.f};

    // ---- prologue: issue chunk 0 into buf0 (8 fire-and-forget loads)
    {
        int rb = rowbase0;
#pragma unroll
        for (int r = 0; r < 4; ++r) {
            int lr_ = w * 4 + r;
            gload_lds16(key + ((size_t)(b * N_NODES + rb + lr_)) * QD + lane * 4,
                        kb0 + lr_ * KSTRIDE);
        }
#pragma unroll
        for (int r = 0; r < 4; ++r) {
            int lr_ = w * 4 + r;
            gload_lds16(value + ((size_t)(b * N_NODES + rb + lr_)) * VD + lane * 4,
                        vb0 + lr_ * 1024);
        }
    }

    for (int t = 0; t < NCH; ++t) {
        __builtin_amdgcn_s_barrier();          // everyone done computing t-1: buf (t+1)&1 free
        if (t + 1 < NCH) {
            char* kbn = ((t + 1) & 1) ? kb1 : kb0;
            char* vbn = ((t + 1) & 1) ? vb1 : vb0;
            int rb = rowbase0 + (t + 1) * CH;
#pragma unroll
            for (int r = 0; r < 4; ++r) {
                int lr_ = w * 4 + r;
                gload_lds16(key + ((size_t)(b * N_NODES + rb + lr_)) * QD + lane * 4,
                            kbn + lr_ * KSTRIDE);
            }
#pragma unroll
            for (int r = 0; r < 4; ++r) {
                int lr_ = w * 4 + r;
                gload_lds16(value + ((size_t)(b * N_NODES + rb + lr_)) * VD + lane * 4,
                            vbn + lr_ * 1024);
            }
            asm volatile("s_waitcnt vmcnt(8)" ::: "memory");   // my chunk-t loads landed
        } else {
            asm volatile("s_waitcnt vmcnt(0)" ::: "memory");
        }
        __builtin_amdgcn_s_barrier();          // everyone's chunk-t loads landed
        __builtin_amdgcn_sched_barrier(0);

        const char* kb = (t & 1) ? kb1 : kb0;
        const char* vb = (t & 1) ? vb1 : vb0;
        int n0c = rowbase0 + t * CH;

        // ---- A-fragments: my half's rows from key LDS (f32 -> bf16)
        bf16x8 a[8];
        {
            int krow = half * 16 + col16;
#pragma unroll
            for (int ks = 0; ks < 8; ++ks) {
                f32x4 lo = *reinterpret_cast<const f32x4*>(kb + krow * KSTRIDE + ks * 128 + g * 32);
                f32x4 hi = *reinterpret_cast<const f32x4*>(kb + krow * KSTRIDE + ks * 128 + g * 32 + 16);
                unsigned int u0, u1, u2, u3;
                asm("v_cvt_pk_bf16_f32 %0, %1, %2" : "=v"(u0) : "v"(lo[0]), "v"(lo[1]));
                asm("v_cvt_pk_bf16_f32 %0, %1, %2" : "=v"(u1) : "v"(lo[2]), "v"(lo[3]));
                asm("v_cvt_pk_bf16_f32 %0, %1, %2" : "=v"(u2) : "v"(hi[0]), "v"(hi[1]));
                asm("v_cvt_pk_bf16_f32 %0, %1, %2" : "=v"(u3) : "v"(hi[2]), "v"(hi[3]));
                uint4 tt = {u0, u1, u2, u3};
                a[ks] = *reinterpret_cast<bf16x8*>(&tt);
            }
        }

        // ---- MFMA: 16 rows x 64 cols (my head), B from registers
        f32x4 acc[4];
#pragma unroll
        for (int ct = 0; ct < 4; ++ct) acc[ct] = (f32x4){0.f, 0.f, 0.f, 0.f};
#pragma unroll
        for (int ks = 0; ks < 8; ++ks)
#pragma unroll
            for (int ct = 0; ct < 4; ++ct)
                acc[ct] = __builtin_amdgcn_mfma_f32_16x16x32_bf16(a[ks], bfr[ks][ct], acc[ct], 0, 0, 0);

        // ---- epilogue: leaky_relu + dot(a) + 16-lane reduce
        float part[4] = {0.f, 0.f, 0.f, 0.f};
#pragma unroll
        for (int ct = 0; ct < 4; ++ct) {
#pragma unroll
            for (int r = 0; r < 4; ++r) {
                float pre = acc[ct][r] + hq4[ct];
                float tv = fmaxf(pre, NEG_SLOPE * pre);
                part[r] += av4[ct] * tv;
            }
        }
#pragma unroll
        for (int off = 1; off < 16; off <<= 1)
#pragma unroll
            for (int r = 0; r < 4; ++r)
                part[r] += __shfl_xor(part[r], off, 64);
        if (col16 == 0) {
            float4 sv4 = {part[0], part[1], part[2], part[3]};
            *reinterpret_cast<float4*>(
                s + ((size_t)(b * NUM_HEADS + h)) * N_NODES + n0c + half * 16 + g * 4) = sv4;
        }

        // ---- online softmax over my 16 rows
        float mc = fmaxf(fmaxf(part[0], part[1]), fmaxf(part[2], part[3]));
        mc = fmaxf(mc, __shfl_xor(mc, 16, 64));
        mc = fmaxf(mc, __shfl_xor(mc, 32, 64));
        float mnew = fmaxf(mr, mc);
        float epv[4];
        float lc = 0.f;
#pragma unroll
        for (int r = 0; r < 4; ++r) { epv[r] = __expf(part[r] - mnew); lc += epv[r]; }
        lc += __shfl_xor(lc, 16, 64);
        lc += __shfl_xor(lc, 32, 64);
        float scf = __expf(mr - mnew);
        pa *= scf;
        lr = lr * scf + lc;
        mr = mnew;

        // ---- PV: my half's 16 value rows from LDS, e broadcast via shfl
#pragma unroll
        for (int n = 0; n < 16; ++n) {
            f32x4 v = *reinterpret_cast<const f32x4*>(vb + (half * 16 + n) * 1024 + lane * 16);
            float e = __shfl(epv[n & 3], (n >> 2) * 16, 64);
            pa += e * v;
        }
    }

    // ---- per-wave output slot
    int slot = bid * 8 + w;
    *reinterpret_cast<f32x4*>(p_part + (size_t)slot * 256 + lane * 4) = pa;
    if (lane == 0) {
        pml[slot * 2] = mr;
        pml[slot * 2 + 1] = lr;
    }
}

// ---------------------------------------------------------------------------
// Kernel 3: final. Per (b,h): 16 slots (8 strips x 2 halves); global M,L;
// rescale-reduce; @Wv + bias + relu; emit (M, invL).
// ---------------------------------------------------------------------------
__global__ __launch_bounds__(256)
void final_kernel(const float* __restrict__ p_part,
                  const float* __restrict__ pml,
                  const float* __restrict__ Wv,
                  const float* __restrict__ bv,
                  float* __restrict__ hout,
                  float* __restrict__ sc) {
    int bh = blockIdx.x;
    int b = bh >> 2, h = bh & 3;
    int tid = threadIdx.x;

    int slots[16];
    float mv[16], lv[16];
    float M = -1e30f;
#pragma unroll
    for (int i = 0; i < 16; ++i) {
        int strip = i >> 1, hf = i & 1;
        slots[i] = (b * 8 + strip) * 8 + hf * 4 + h;
        mv[i] = pml[slots[i] * 2];
        lv[i] = pml[slots[i] * 2 + 1];
        M = fmaxf(M, mv[i]);
    }
    float L = 0.f, acc = 0.f;
#pragma unroll
    for (int i = 0; i < 16; ++i) {
        float wf = __expf(mv[i] - M);
        L += wf * lv[i];
        acc += wf * p_part[(size_t)slots[i] * 256 + tid];
    }
    float invL = 1.0f / L;
    if (tid == 0) {
        sc[bh * 2] = M;
        sc[bh * 2 + 1] = invL;
    }
    __shared__ float ps[256];
    ps[tid] = acc * invL;
    __syncthreads();

    int d = tid & 63, kr = tid >> 6;
    float a2 = 0.f;
#pragma unroll 8
    for (int k = kr * 64; k < kr * 64 + 64; ++k)
        a2 += ps[k] * Wv[k * HD + h * 64 + d];
    __shared__ float rs[4][64];
    rs[kr][d] = a2;
    __syncthreads();
    if (tid < 64) {
        float o = bv[h * 64 + tid] + rs[0][tid] + rs[1][tid] + rs[2][tid] + rs[3][tid];
        hout[b * HD + h * 64 + tid] = fmaxf(o, 0.f);
    }
}

// ---------------------------------------------------------------------------
// Kernel 4: e-pass. e_out[b,n,h] = exp(s[b,h,n]-M)*invL.
// ---------------------------------------------------------------------------
__global__ __launch_bounds__(256)
void epass_kernel(const float* __restrict__ s,
                  const float* __restrict__ sc,
                  float* __restrict__ e_out) {
    int bid = blockIdx.x;
    int b = bid >> 5, t = bid & 31;
    int n = t * 256 + threadIdx.x;
    float4 ev;
#pragma unroll
    for (int h = 0; h < 4; ++h) {
        float M = sc[(b * 4 + h) * 2];
        float invL = sc[(b * 4 + h) * 2 + 1];
        float sv = s[((size_t)(b * 4 + h)) * N_NODES + n];
        (&ev.x)[h] = __expf(sv - M) * invL;
    }
    *reinterpret_cast<float4*>(e_out + ((size_t)(b * N_NODES + n)) * 4) = ev;
}

extern "C" void kernel_launch(void* const* d_in, const int* in_sizes, int n_in,
                              void* d_out, int out_size, void* d_ws, size_t ws_size,
                              hipStream_t stream) {
    const float* query = (const float*)d_in[0];
    const float* key   = (const float*)d_in[1];
    const float* value = (const float*)d_in[2];
    const float* Wq    = (const float*)d_in[3];
    const float* bq    = (const float*)d_in[4];
    const float* Wv    = (const float*)d_in[5];
    const float* bv    = (const float*)d_in[6];
    const float* avec  = (const float*)d_in[7];
    float* out = (float*)d_out;

    char* ws = (char*)d_ws;
    unsigned short* WqP = (unsigned short*)ws;               // 128 KB
    float* hqb    = (float*)(ws + 131072);                   // 32 KB
    float* s      = (float*)(ws + 163840);                   // 4 MB
    float* pml    = (float*)(ws + 4358144);                  // 16 KB
    float* sc     = (float*)(ws + 4374528);                  // 4 KB
    float* p_part = (float*)(ws + 4378624);                  // 2 MB

    prep_kernel<<<64, 256, 0, stream>>>(query, Wq, bq, WqP, hqb);
    fused_kernel<<<256, 512, 0, stream>>>(key, value, WqP, hqb, avec, s, p_part, pml);
    final_kernel<<<B_SZ * NUM_HEADS, 256, 0, stream>>>(p_part, pml, Wv, bv, out, sc);
    epass_kernel<<<B_SZ * 32, 256, 0, stream>>>(s, sc, out + B_SZ * HD);
}

// Round 14
// 128.168 us; speedup vs baseline: 1.2933x; 1.0232x over previous
//
#include <hip/hip_runtime.h>
#include <hip/hip_bf16.h>

#define NUM_HEADS 4
#define HD 256
#define QD 256
#define VD 256
#define B_SZ 32
#define N_NODES 8192
#define NEG_SLOPE 0.2f
#define CH 32            // rows per chunk
#define NCH 32           // chunks per strip (1024 rows)
#define KSTRIDE 1040     // key LDS row stride bytes (16B-aligned pad)

typedef short bf16x8 __attribute__((ext_vector_type(8)));
typedef float f32x4 __attribute__((ext_vector_type(4)));

static __device__ __forceinline__ unsigned short f2bf(float f) {
    __hip_bfloat16 h = __float2bfloat16(f);
    return *reinterpret_cast<unsigned short*>(&h);
}

// async global->LDS, 16B/lane: LDS dest = base + lane*16; global src per-lane.
static __device__ __forceinline__ void gload_lds16(const float* g, void* l) {
    __builtin_amdgcn_global_load_lds(
        (const __attribute__((address_space(1))) void*)g,
        (__attribute__((address_space(3))) void*)l, 16, 0, 0);
}

// ---------------------------------------------------------------------------
// Kernel 1: prep  (hqb + swizzled WqP pack; unchanged)
// ---------------------------------------------------------------------------
__global__ __launch_bounds__(256)
void prep_kernel(const float* __restrict__ query,
                 const float* __restrict__ Wq,
                 const float* __restrict__ bq,
                 unsigned short* __restrict__ WqP,
                 float* __restrict__ hqb) {
    int blk = blockIdx.x;
    int tid = threadIdx.x;
    if (blk < 32) {
        int b = blk, col = tid;
        float acc = 2.0f * bq[col];
#pragma unroll 16
        for (int k = 0; k < QD; ++k)
            acc += query[b * QD + k] * Wq[k * HD + col];
        hqb[b * HD + col] = acc;
    } else {
        int idx = blk - 32;
        int kstep = idx >> 2, g = idx & 3;
        int col = tid;
        int h = col >> 6, ct = (col >> 4) & 3, col16 = col & 15;
        unsigned short v[8];
#pragma unroll
        for (int j = 0; j < 8; ++j)
            v[j] = f2bf(Wq[(kstep * 32 + g * 8 + j) * HD + col]);
        *reinterpret_cast<uint4*>(
            WqP + kstep * 8192 + h * 2048 + ct * 512 + (g * 16 + col16) * 8) =
            *reinterpret_cast<uint4*>(v);
    }
}

// ---------------------------------------------------------------------------
// Kernel 2 (FUSED, R13 pipeline + swapped-operand MFMA epilogue):
// mfma(bfr_wq, a_key): C rows = d (reg dim), C cols = key row (lane&15).
// a-dot over d reduces over REGISTERS (+2 shfl) instead of 16 shfl;
// softmax reduces over the col16 group (4+4 shfl). ~26 shfl/wave/chunk
// vs 36, and no 4-reg shfl chains -> less LDS-pipe + VALU pressure.
// ---------------------------------------------------------------------------
__global__ __launch_bounds__(512, 2)
void fused_kernel(const float* __restrict__ key,
                  const float* __restrict__ value,
                  const unsigned short* __restrict__ WqP,
                  const float* __restrict__ hqb,
                  const float* __restrict__ avec,
                  float* __restrict__ s,
                  float* __restrict__ p_part,
                  float* __restrict__ pml) {
    __shared__ __align__(16) char smem[2 * (CH * KSTRIDE) + 2 * (CH * 1024)];  // 132096 B

    char* kb0 = smem;
    char* kb1 = smem + CH * KSTRIDE;
    char* vb0 = smem + 2 * CH * KSTRIDE;
    char* vb1 = vb0 + CH * 1024;

    int bid = blockIdx.x;
    int b = bid >> 3, strip = bid & 7;
    int tid = threadIdx.x;
    int w = tid >> 6, lane = tid & 63;
    int col16 = lane & 15, g = (lane >> 4) & 3;   // g doubles as d-group in C
    int h = w & 3, half = w >> 2;
    int rowbase0 = strip * 1024;

    // ---- persistent B-fragments for my head: 32 x bf16x8 = 128 VGPRs
    bf16x8 bfr[8][4];
    {
        const unsigned short* wp0 = WqP + h * 2048 + (g * 16 + col16) * 8;
#pragma unroll
        for (int ks = 0; ks < 8; ++ks)
#pragma unroll
            for (int ct = 0; ct < 4; ++ct)
                bfr[ks][ct] = *reinterpret_cast<const bf16x8*>(wp0 + ks * 8192 + ct * 512);
    }
    // per-lane d-constants: d = ct*16 + g*4 + r  (C row mapping, m89)
    float av16[4][4], hq16[4][4];
#pragma unroll
    for (int ct = 0; ct < 4; ++ct)
#pragma unroll
        for (int r = 0; r < 4; ++r) {
            int d = ct * 16 + g * 4 + r;
            av16[ct][r] = avec[d];
            hq16[ct][r] = hqb[b * HD + h * 64 + d];
        }

    // ---- running online-softmax state (single head)
    float mr = -1e30f, lr = 0.f;
    f32x4 pa = (f32x4){0.f, 0.f, 0.f, 0.f};

    // ---- prologue: issue chunk 0 into buf0 (8 fire-and-forget loads)
    {
        int rb = rowbase0;
#pragma unroll
        for (int r = 0; r < 4; ++r) {
            int lr_ = w * 4 + r;
            gload_lds16(key + ((size_t)(b * N_NODES + rb + lr_)) * QD + lane * 4,
                        kb0 + lr_ * KSTRIDE);
        }
#pragma unroll
        for (int r = 0; r < 4; ++r) {
            int lr_ = w * 4 + r;
            gload_lds16(value + ((size_t)(b * N_NODES + rb + lr_)) * VD + lane * 4,
                        vb0 + lr_ * 1024);
        }
    }

    for (int t = 0; t < NCH; ++t) {
        __builtin_amdgcn_s_barrier();          // everyone done computing t-1
        if (t + 1 < NCH) {
            char* kbn = ((t + 1) & 1) ? kb1 : kb0;
            char* vbn = ((t + 1) & 1) ? vb1 : vb0;
            int rb = rowbase0 + (t + 1) * CH;
#pragma unroll
            for (int r = 0; r < 4; ++r) {
                int lr_ = w * 4 + r;
                gload_lds16(key + ((size_t)(b * N_NODES + rb + lr_)) * QD + lane * 4,
                            kbn + lr_ * KSTRIDE);
            }
#pragma unroll
            for (int r = 0; r < 4; ++r) {
                int lr_ = w * 4 + r;
                gload_lds16(value + ((size_t)(b * N_NODES + rb + lr_)) * VD + lane * 4,
                            vbn + lr_ * 1024);
            }
            asm volatile("s_waitcnt vmcnt(8)" ::: "memory");   // my chunk-t loads landed
        } else {
            asm volatile("s_waitcnt vmcnt(0)" ::: "memory");
        }
        __builtin_amdgcn_s_barrier();          // everyone's chunk-t loads landed
        __builtin_amdgcn_sched_barrier(0);

        const char* kb = (t & 1) ? kb1 : kb0;
        const char* vb = (t & 1) ? vb1 : vb0;
        int n0c = rowbase0 + t * CH;

        // ---- A-side fragments from key LDS (f32 -> bf16); lane&15 = key row
        bf16x8 a[8];
        {
            int krow = half * 16 + col16;
#pragma unroll
            for (int ks = 0; ks < 8; ++ks) {
                f32x4 lo = *reinterpret_cast<const f32x4*>(kb + krow * KSTRIDE + ks * 128 + g * 32);
                f32x4 hi = *reinterpret_cast<const f32x4*>(kb + krow * KSTRIDE + ks * 128 + g * 32 + 16);
                unsigned int u0, u1, u2, u3;
                asm("v_cvt_pk_bf16_f32 %0, %1, %2" : "=v"(u0) : "v"(lo[0]), "v"(lo[1]));
                asm("v_cvt_pk_bf16_f32 %0, %1, %2" : "=v"(u1) : "v"(lo[2]), "v"(lo[3]));
                asm("v_cvt_pk_bf16_f32 %0, %1, %2" : "=v"(u2) : "v"(hi[0]), "v"(hi[1]));
                asm("v_cvt_pk_bf16_f32 %0, %1, %2" : "=v"(u3) : "v"(hi[2]), "v"(hi[3]));
                uint4 tt = {u0, u1, u2, u3};
                a[ks] = *reinterpret_cast<bf16x8*>(&tt);
            }
        }

        // ---- MFMA swapped: C[d][keyrow] = sum_k Wq[k][d]*key[keyrow][k]
        f32x4 acc[4];
#pragma unroll
        for (int ct = 0; ct < 4; ++ct) acc[ct] = (f32x4){0.f, 0.f, 0.f, 0.f};
#pragma unroll
        for (int ks = 0; ks < 8; ++ks)
#pragma unroll
            for (int ct = 0; ct < 4; ++ct)
                acc[ct] = __builtin_amdgcn_mfma_f32_16x16x32_bf16(bfr[ks][ct], a[ks], acc[ct], 0, 0, 0);

        // ---- epilogue: leaky + a-dot over d (regs) + 2 shfl over d-groups
        float dot = 0.f;
#pragma unroll
        for (int ct = 0; ct < 4; ++ct) {
#pragma unroll
            for (int r = 0; r < 4; ++r) {
                float pre = acc[ct][r] + hq16[ct][r];
                float tv = fmaxf(pre, NEG_SLOPE * pre);
                dot += av16[ct][r] * tv;
            }
        }
        dot += __shfl_xor(dot, 16, 64);
        dot += __shfl_xor(dot, 32, 64);
        // dot = full score for key row col16 (dup across the 4 d-groups)

        if (lane < 16) {
            s[((size_t)(b * NUM_HEADS + h)) * N_NODES + n0c + half * 16 + lane] = dot;
        }

        // ---- online softmax over my 16 rows (reduce over col16 group)
        float mc = dot;
        mc = fmaxf(mc, __shfl_xor(mc, 1, 64));
        mc = fmaxf(mc, __shfl_xor(mc, 2, 64));
        mc = fmaxf(mc, __shfl_xor(mc, 4, 64));
        mc = fmaxf(mc, __shfl_xor(mc, 8, 64));
        float mnew = fmaxf(mr, mc);
        float ep = __expf(dot - mnew);      // my row's exp (dup across groups)
        float lc = ep;
        lc += __shfl_xor(lc, 1, 64);
        lc += __shfl_xor(lc, 2, 64);
        lc += __shfl_xor(lc, 4, 64);
        lc += __shfl_xor(lc, 8, 64);
        float scf = __expf(mr - mnew);
        pa *= scf;
        lr = lr * scf + lc;
        mr = mnew;

        // ---- PV: my half's 16 value rows from LDS, e broadcast via shfl
#pragma unroll
        for (int n = 0; n < 16; ++n) {
            f32x4 v = *reinterpret_cast<const f32x4*>(vb + (half * 16 + n) * 1024 + lane * 16);
            float e = __shfl(ep, n, 64);    // lane n holds row n's exp
            pa += e * v;
        }
    }

    // ---- per-wave output slot
    int slot = bid * 8 + w;
    *reinterpret_cast<f32x4*>(p_part + (size_t)slot * 256 + lane * 4) = pa;
    if (lane == 0) {
        pml[slot * 2] = mr;
        pml[slot * 2 + 1] = lr;
    }
}

// ---------------------------------------------------------------------------
// Kernel 3: final. Per (b,h): 16 slots (8 strips x 2 halves); global M,L;
// rescale-reduce; @Wv + bias + relu; emit (M, invL).
// ---------------------------------------------------------------------------
__global__ __launch_bounds__(256)
void final_kernel(const float* __restrict__ p_part,
                  const float* __restrict__ pml,
                  const float* __restrict__ Wv,
                  const float* __restrict__ bv,
                  float* __restrict__ hout,
                  float* __restrict__ sc) {
    int bh = blockIdx.x;
    int b = bh >> 2, h = bh & 3;
    int tid = threadIdx.x;

    int slots[16];
    float mv[16], lv[16];
    float M = -1e30f;
#pragma unroll
    for (int i = 0; i < 16; ++i) {
        int strip = i >> 1, hf = i & 1;
        slots[i] = (b * 8 + strip) * 8 + hf * 4 + h;
        mv[i] = pml[slots[i] * 2];
        lv[i] = pml[slots[i] * 2 + 1];
        M = fmaxf(M, mv[i]);
    }
    float L = 0.f, acc = 0.f;
#pragma unroll
    for (int i = 0; i < 16; ++i) {
        float wf = __expf(mv[i] - M);
        L += wf * lv[i];
        acc += wf * p_part[(size_t)slots[i] * 256 + tid];
    }
    float invL = 1.0f / L;
    if (tid == 0) {
        sc[bh * 2] = M;
        sc[bh * 2 + 1] = invL;
    }
    __shared__ float ps[256];
    ps[tid] = acc * invL;
    __syncthreads();

    int d = tid & 63, kr = tid >> 6;
    float a2 = 0.f;
#pragma unroll 8
    for (int k = kr * 64; k < kr * 64 + 64; ++k)
        a2 += ps[k] * Wv[k * HD + h * 64 + d];
    __shared__ float rs[4][64];
    rs[kr][d] = a2;
    __syncthreads();
    if (tid < 64) {
        float o = bv[h * 64 + tid] + rs[0][tid] + rs[1][tid] + rs[2][tid] + rs[3][tid];
        hout[b * HD + h * 64 + tid] = fmaxf(o, 0.f);
    }
}

// ---------------------------------------------------------------------------
// Kernel 4: e-pass. e_out[b,n,h] = exp(s[b,h,n]-M)*invL.
// ---------------------------------------------------------------------------
__global__ __launch_bounds__(256)
void epass_kernel(const float* __restrict__ s,
                  const float* __restrict__ sc,
                  float* __restrict__ e_out) {
    int bid = blockIdx.x;
    int b = bid >> 5, t = bid & 31;
    int n = t * 256 + threadIdx.x;
    float4 ev;
#pragma unroll
    for (int h = 0; h < 4; ++h) {
        float M = sc[(b * 4 + h) * 2];
        float invL = sc[(b * 4 + h) * 2 + 1];
        float sv = s[((size_t)(b * 4 + h)) * N_NODES + n];
        (&ev.x)[h] = __expf(sv - M) * invL;
    }
    *reinterpret_cast<float4*>(e_out + ((size_t)(b * N_NODES + n)) * 4) = ev;
}

extern "C" void kernel_launch(void* const* d_in, const int* in_sizes, int n_in,
                              void* d_out, int out_size, void* d_ws, size_t ws_size,
                              hipStream_t stream) {
    const float* query = (const float*)d_in[0];
    const float* key   = (const float*)d_in[1];
    const float* value = (const float*)d_in[2];
    const float* Wq    = (const float*)d_in[3];
    const float* bq    = (const float*)d_in[4];
    const float* Wv    = (const float*)d_in[5];
    const float* bv    = (const float*)d_in[6];
    const float* avec  = (const float*)d_in[7];
    float* out = (float*)d_out;

    char* ws = (char*)d_ws;
    unsigned short* WqP = (unsigned short*)ws;               // 128 KB
    float* hqb    = (float*)(ws + 131072);                   // 32 KB
    float* s      = (float*)(ws + 163840);                   // 4 MB
    float* pml    = (float*)(ws + 4358144);                  // 16 KB
    float* sc     = (float*)(ws + 4374528);                  // 4 KB
    float* p_part = (float*)(ws + 4378624);                  // 2 MB

    prep_kernel<<<64, 256, 0, stream>>>(query, Wq, bq, WqP, hqb);
    fused_kernel<<<256, 512, 0, stream>>>(key, value, WqP, hqb, avec, s, p_part, pml);
    final_kernel<<<B_SZ * NUM_HEADS, 256, 0, stream>>>(p_part, pml, Wv, bv, out, sc);
    epass_kernel<<<B_SZ * 32, 256, 0, stream>>>(s, sc, out + B_SZ * HD);
}